// Round 3
// baseline (551.136 us; speedup 1.0000x reference)
//
#include <hip/hip_runtime.h>

constexpr int NNODES = 100000;
constexpr int NEDGES = 1600000;
constexpr int K = 128;
constexpr int NB1 = (NNODES + 255) / 256;   // 391 scan blocks

__global__ void zero_int_kernel(int* __restrict__ p, int n) {
    int i = blockIdx.x * 256 + threadIdx.x;
    if (i < n) p[i] = 0;
}

// 4 edges per thread, independent atomics for ILP
__global__ void hist_kernel(const int* __restrict__ dst, int* __restrict__ deg) {
    int base = (blockIdx.x * 256 + threadIdx.x) * 4;
    if (base + 4 <= NEDGES) {
        int4 d = *reinterpret_cast<const int4*>(dst + base);
        atomicAdd(&deg[d.x], 1);
        atomicAdd(&deg[d.y], 1);
        atomicAdd(&deg[d.z], 1);
        atomicAdd(&deg[d.w], 1);
    } else {
        for (int e = base; e < NEDGES; ++e) atomicAdd(&deg[dst[e]], 1);
    }
}

// exclusive scan, stage 1: per-256-block scan + block sums
__global__ void scan1_kernel(const int* __restrict__ deg, int* __restrict__ row_start,
                             int* __restrict__ blocksum) {
    __shared__ int tmp[256];
    int i = blockIdx.x * 256 + threadIdx.x;
    int v = (i < NNODES) ? deg[i] : 0;
    tmp[threadIdx.x] = v;
    __syncthreads();
    #pragma unroll
    for (int off = 1; off < 256; off <<= 1) {
        int t = (threadIdx.x >= off) ? tmp[threadIdx.x - off] : 0;
        __syncthreads();
        tmp[threadIdx.x] += t;
        __syncthreads();
    }
    if (i < NNODES) row_start[i] = tmp[threadIdx.x] - v;   // exclusive
    if (threadIdx.x == 255) blocksum[blockIdx.x] = tmp[255];
}

// stage 2: single block scans the 391 block sums (exclusive)
__global__ void scan2_kernel(int* __restrict__ blocksum, int* __restrict__ blockoff) {
    __shared__ int tmp[512];
    int t = threadIdx.x;
    int v = (t < NB1) ? blocksum[t] : 0;
    tmp[t] = v;
    __syncthreads();
    #pragma unroll
    for (int off = 1; off < 512; off <<= 1) {
        int u = (t >= off) ? tmp[t - off] : 0;
        __syncthreads();
        tmp[t] += u;
        __syncthreads();
    }
    if (t < NB1) blockoff[t] = tmp[t] - v;
}

// stage 3: add block offsets, init cursor = row_start
__global__ void scan3_kernel(int* __restrict__ row_start, const int* __restrict__ blockoff,
                             int* __restrict__ cursor) {
    int i = blockIdx.x * 256 + threadIdx.x;
    if (i < NNODES) {
        int rs = row_start[i] + blockoff[blockIdx.x];
        row_start[i] = rs;
        cursor[i] = rs;
    }
}

// fill CSR adjacency, 4 edges/thread for ILP; cursor ends up = row_end
__global__ void fill_kernel(const int* __restrict__ src, const int* __restrict__ dst,
                            int* __restrict__ cursor, int* __restrict__ csr_src) {
    int base = (blockIdx.x * 256 + threadIdx.x) * 4;
    if (base + 4 <= NEDGES) {
        int4 d = *reinterpret_cast<const int4*>(dst + base);
        int4 s = *reinterpret_cast<const int4*>(src + base);
        int p0 = atomicAdd(&cursor[d.x], 1);
        int p1 = atomicAdd(&cursor[d.y], 1);
        int p2 = atomicAdd(&cursor[d.z], 1);
        int p3 = atomicAdd(&cursor[d.w], 1);
        csr_src[p0] = s.x;
        csr_src[p1] = s.y;
        csr_src[p2] = s.z;
        csr_src[p3] = s.w;
    } else {
        for (int e = base; e < NEDGES; ++e) {
            int pos = atomicAdd(&cursor[dst[e]], 1);
            csr_src[pos] = src[e];
        }
    }
}

// out[n] = mean over incoming neighbors of feat[src] (+ add[n] if ADDV)
template<int F, bool ADDV>
__global__ void gather_mean_kernel(const int* __restrict__ row_start,
                                   const int* __restrict__ row_end,
                                   const int* __restrict__ csr_src,
                                   const float* __restrict__ feat,
                                   const float* __restrict__ add,
                                   float* __restrict__ out) {
    constexpr int G = F / 4;        // lanes per node (32 or 16)
    constexpr int NPB = 256 / G;    // nodes per block (8 or 16)
    int node = blockIdx.x * NPB + threadIdx.x / G;
    int lane = threadIdx.x % G;
    if (node >= NNODES) return;
    int beg = row_start[node];
    int end = row_end[node];
    float4 a0 = make_float4(0.f, 0.f, 0.f, 0.f);
    float4 a1 = make_float4(0.f, 0.f, 0.f, 0.f);
    float4 a2 = make_float4(0.f, 0.f, 0.f, 0.f);
    float4 a3 = make_float4(0.f, 0.f, 0.f, 0.f);
    int j = beg;
    for (; j + 3 < end; j += 4) {
        int s0 = csr_src[j];
        int s1 = csr_src[j + 1];
        int s2 = csr_src[j + 2];
        int s3 = csr_src[j + 3];
        float4 v0 = *reinterpret_cast<const float4*>(feat + (size_t)s0 * F + lane * 4);
        float4 v1 = *reinterpret_cast<const float4*>(feat + (size_t)s1 * F + lane * 4);
        float4 v2 = *reinterpret_cast<const float4*>(feat + (size_t)s2 * F + lane * 4);
        float4 v3 = *reinterpret_cast<const float4*>(feat + (size_t)s3 * F + lane * 4);
        a0.x += v0.x; a0.y += v0.y; a0.z += v0.z; a0.w += v0.w;
        a1.x += v1.x; a1.y += v1.y; a1.z += v1.z; a1.w += v1.w;
        a2.x += v2.x; a2.y += v2.y; a2.z += v2.z; a2.w += v2.w;
        a3.x += v3.x; a3.y += v3.y; a3.z += v3.z; a3.w += v3.w;
    }
    for (; j < end; ++j) {
        int s0 = csr_src[j];
        float4 v0 = *reinterpret_cast<const float4*>(feat + (size_t)s0 * F + lane * 4);
        a0.x += v0.x; a0.y += v0.y; a0.z += v0.z; a0.w += v0.w;
    }
    float inv = 1.0f / fmaxf((float)(end - beg), 1.0f);
    float4 o;
    o.x = (a0.x + a1.x + a2.x + a3.x) * inv;
    o.y = (a0.y + a1.y + a2.y + a3.y) * inv;
    o.z = (a0.z + a1.z + a2.z + a3.z) * inv;
    o.w = (a0.w + a1.w + a2.w + a3.w) * inv;
    if (ADDV) {
        float4 av = *reinterpret_cast<const float4*>(add + (size_t)node * F + lane * 4);
        o.x += av.x; o.y += av.y; o.z += av.z; o.w += av.w;
    }
    *reinterpret_cast<float4*>(out + (size_t)node * F + lane * 4) = o;
}

// C[r] = epi( A1[r]@Wa (+ A2[r]@Wb) + bias ); K=128 fixed.
template<int NOUT, bool TWO, bool RELU, bool BIAS>
__global__ __launch_bounds__(256, 2) void gemm_kernel(
    const float* __restrict__ A1, const float* __restrict__ Wa,
    const float* __restrict__ A2, const float* __restrict__ Wb,
    const float* __restrict__ bias,
    float* __restrict__ C, int M)
{
    constexpr int TM  = 64;
    constexpr int KC  = 32;
    constexpr int CT  = NOUT / 4;
    constexpr int RT  = 256 / CT;
    constexpr int RPT = TM / RT;

    __shared__ float As[KC][TM + 4];
    __shared__ float Ws[KC][NOUT];

    const int tid  = threadIdx.x;
    const int row0 = blockIdx.x * TM;

    const int arow   = tid >> 2;
    const int kq     = (tid & 3) * 8;
    const int lrow   = row0 + arow;
    const bool lvalid = lrow < M;

    const int tc = tid % CT;
    const int tr = tid / CT;

    float acc[RPT][4];
    #pragma unroll
    for (int i = 0; i < RPT; ++i)
        #pragma unroll
        for (int j = 0; j < 4; ++j) acc[i][j] = 0.f;

    #pragma unroll
    for (int mm = 0; mm < (TWO ? 2 : 1); ++mm) {
        const float* __restrict__ A = mm ? A2 : A1;
        const float* __restrict__ W = mm ? Wb : Wa;
        for (int kk = 0; kk < K; kk += KC) {
            float va[8];
            if (lvalid) {
                const float* ap = A + (size_t)lrow * K + kk + kq;
                float4 v0 = *reinterpret_cast<const float4*>(ap);
                float4 v1 = *reinterpret_cast<const float4*>(ap + 4);
                va[0] = v0.x; va[1] = v0.y; va[2] = v0.z; va[3] = v0.w;
                va[4] = v1.x; va[5] = v1.y; va[6] = v1.z; va[7] = v1.w;
            } else {
                #pragma unroll
                for (int j = 0; j < 8; ++j) va[j] = 0.f;
            }
            #pragma unroll
            for (int j = 0; j < 8; ++j) As[kq + j][arow] = va[j];

            constexpr int WQ = KC * NOUT / 4 / 256;
            const float4* wg = reinterpret_cast<const float4*>(W + kk * NOUT);
            float4* wl = reinterpret_cast<float4*>(&Ws[0][0]);
            #pragma unroll
            for (int q = 0; q < WQ; ++q) wl[tid + q * 256] = wg[tid + q * 256];

            __syncthreads();
            #pragma unroll
            for (int k = 0; k < KC; ++k) {
                float4 w = *reinterpret_cast<const float4*>(&Ws[k][tc * 4]);
                float a[RPT];
                #pragma unroll
                for (int q = 0; q < RPT; q += 4) {
                    float4 av = *reinterpret_cast<const float4*>(&As[k][tr * RPT + q]);
                    a[q] = av.x; a[q + 1] = av.y; a[q + 2] = av.z; a[q + 3] = av.w;
                }
                #pragma unroll
                for (int i = 0; i < RPT; ++i) {
                    acc[i][0] = fmaf(a[i], w.x, acc[i][0]);
                    acc[i][1] = fmaf(a[i], w.y, acc[i][1]);
                    acc[i][2] = fmaf(a[i], w.z, acc[i][2]);
                    acc[i][3] = fmaf(a[i], w.w, acc[i][3]);
                }
            }
            __syncthreads();
        }
    }

    float4 bv = make_float4(0.f, 0.f, 0.f, 0.f);
    if (BIAS) bv = *reinterpret_cast<const float4*>(bias + tc * 4);
    #pragma unroll
    for (int i = 0; i < RPT; ++i) {
        int r = row0 + tr * RPT + i;
        if (r >= M) continue;
        float4 o;
        o.x = acc[i][0] + bv.x; o.y = acc[i][1] + bv.y;
        o.z = acc[i][2] + bv.z; o.w = acc[i][3] + bv.w;
        if (RELU) {
            o.x = fmaxf(o.x, 0.f); o.y = fmaxf(o.y, 0.f);
            o.z = fmaxf(o.z, 0.f); o.w = fmaxf(o.w, 0.f);
        }
        *reinterpret_cast<float4*>(C + (size_t)r * NOUT + tc * 4) = o;
    }
}

// dual-output: P = A@Wl, R = A@Wr + bias   (single pass over A; NOUT=64, K=128)
__global__ __launch_bounds__(256, 2) void gemm2out_kernel(
    const float* __restrict__ A, const float* __restrict__ Wl,
    const float* __restrict__ Wr, const float* __restrict__ bias,
    float* __restrict__ P, float* __restrict__ R, int M)
{
    constexpr int TM = 64, KC = 32, NOUT = 64;
    constexpr int CT = 16, RPT = 4;     // 16 col-threads x 16 row-threads, 4 rows each

    __shared__ float As[KC][TM + 4];
    __shared__ float Wsl[KC][NOUT];
    __shared__ float Wsr[KC][NOUT];

    const int tid  = threadIdx.x;
    const int row0 = blockIdx.x * TM;
    const int arow = tid >> 2;
    const int kq   = (tid & 3) * 8;
    const int lrow = row0 + arow;
    const bool lvalid = lrow < M;
    const int tc = tid % CT;
    const int tr = tid / CT;

    float accp[RPT][4], accr[RPT][4];
    #pragma unroll
    for (int i = 0; i < RPT; ++i)
        #pragma unroll
        for (int j = 0; j < 4; ++j) { accp[i][j] = 0.f; accr[i][j] = 0.f; }

    for (int kk = 0; kk < K; kk += KC) {
        float va[8];
        if (lvalid) {
            const float* ap = A + (size_t)lrow * K + kk + kq;
            float4 v0 = *reinterpret_cast<const float4*>(ap);
            float4 v1 = *reinterpret_cast<const float4*>(ap + 4);
            va[0] = v0.x; va[1] = v0.y; va[2] = v0.z; va[3] = v0.w;
            va[4] = v1.x; va[5] = v1.y; va[6] = v1.z; va[7] = v1.w;
        } else {
            #pragma unroll
            for (int j = 0; j < 8; ++j) va[j] = 0.f;
        }
        #pragma unroll
        for (int j = 0; j < 8; ++j) As[kq + j][arow] = va[j];

        // each W chunk: 32x64 floats = 512 float4; 256 threads -> 2 each
        const float4* wgl = reinterpret_cast<const float4*>(Wl + kk * NOUT);
        const float4* wgr = reinterpret_cast<const float4*>(Wr + kk * NOUT);
        float4* wll = reinterpret_cast<float4*>(&Wsl[0][0]);
        float4* wlr = reinterpret_cast<float4*>(&Wsr[0][0]);
        wll[tid] = wgl[tid]; wll[tid + 256] = wgl[tid + 256];
        wlr[tid] = wgr[tid]; wlr[tid + 256] = wgr[tid + 256];

        __syncthreads();
        #pragma unroll
        for (int k = 0; k < KC; ++k) {
            float4 wl4 = *reinterpret_cast<const float4*>(&Wsl[k][tc * 4]);
            float4 wr4 = *reinterpret_cast<const float4*>(&Wsr[k][tc * 4]);
            float4 av = *reinterpret_cast<const float4*>(&As[k][tr * RPT]);
            float a[RPT] = {av.x, av.y, av.z, av.w};
            #pragma unroll
            for (int i = 0; i < RPT; ++i) {
                accp[i][0] = fmaf(a[i], wl4.x, accp[i][0]);
                accp[i][1] = fmaf(a[i], wl4.y, accp[i][1]);
                accp[i][2] = fmaf(a[i], wl4.z, accp[i][2]);
                accp[i][3] = fmaf(a[i], wl4.w, accp[i][3]);
                accr[i][0] = fmaf(a[i], wr4.x, accr[i][0]);
                accr[i][1] = fmaf(a[i], wr4.y, accr[i][1]);
                accr[i][2] = fmaf(a[i], wr4.z, accr[i][2]);
                accr[i][3] = fmaf(a[i], wr4.w, accr[i][3]);
            }
        }
        __syncthreads();
    }

    float4 bv = *reinterpret_cast<const float4*>(bias + tc * 4);
    #pragma unroll
    for (int i = 0; i < RPT; ++i) {
        int r = row0 + tr * RPT + i;
        if (r >= M) continue;
        float4 op, orr;
        op.x = accp[i][0]; op.y = accp[i][1]; op.z = accp[i][2]; op.w = accp[i][3];
        orr.x = accr[i][0] + bv.x; orr.y = accr[i][1] + bv.y;
        orr.z = accr[i][2] + bv.z; orr.w = accr[i][3] + bv.w;
        *reinterpret_cast<float4*>(P + (size_t)r * NOUT + tc * 4) = op;
        *reinterpret_cast<float4*>(R + (size_t)r * NOUT + tc * 4) = orr;
    }
}

extern "C" void kernel_launch(void* const* d_in, const int* in_sizes, int n_in,
                              void* d_out, int out_size, void* d_ws, size_t ws_size,
                              hipStream_t stream)
{
    const float* x   = (const float*)d_in[0];
    const int*   ei  = (const int*)d_in[1];
    const float* W1l = (const float*)d_in[2];
    const float* W1r = (const float*)d_in[3];
    const float* b1  = (const float*)d_in[4];
    const float* W2l = (const float*)d_in[5];
    const float* W2r = (const float*)d_in[6];
    const float* b2  = (const float*)d_in[7];
    const int* src = ei;
    const int* dst = ei + NEDGES;

    char* ws = (char*)d_ws;
    int*   deg_i     = (int*)(ws + 0);             // 400,000 B
    int*   row_start = (int*)(ws + 400128);        // 400,000 B
    int*   cursor    = (int*)(ws + 800256);        // 400,000 B (becomes row_end)
    int*   blocksum  = (int*)(ws + 1200384);
    int*   blockoff  = (int*)(ws + 1202048);
    int*   csr_src   = (int*)(ws + 1203712);       // 6,400,000 B
    float* agg1      = (float*)(ws + 7603712);     // 51,200,000 B (layer-1 agg)
    float* p         = agg1;                       // N*64 (reuse, layer-2 proj)
    float* r         = (float*)(ws + 7603712 + 25600000);  // N*64
    float* h         = (float*)(ws + 58803712);    // 51,200,000 B
    float* out       = (float*)d_out;

    // ---- build CSR (shared by both layers) ----
    zero_int_kernel<<<(NNODES + 255) / 256, 256, 0, stream>>>(deg_i, NNODES);
    hist_kernel<<<(NEDGES / 4 + 255) / 256, 256, 0, stream>>>(dst, deg_i);
    scan1_kernel<<<NB1, 256, 0, stream>>>(deg_i, row_start, blocksum);
    scan2_kernel<<<1, 512, 0, stream>>>(blocksum, blockoff);
    scan3_kernel<<<NB1, 256, 0, stream>>>(row_start, blockoff, cursor);
    fill_kernel<<<(NEDGES / 4 + 255) / 256, 256, 0, stream>>>(src, dst, cursor, csr_src);

    // ---- layer 1 ----
    gather_mean_kernel<128, false><<<(NNODES + 7) / 8, 256, 0, stream>>>(
        row_start, cursor, csr_src, x, nullptr, agg1);
    gemm_kernel<128, true, true, true>
        <<<(NNODES + 63) / 64, 256, 0, stream>>>(agg1, W1l, x, W1r, b1, h, NNODES);

    // ---- layer 2: p = h@W2_l, r = h@W2_r + b2 in one pass; out = mean(p) + r ----
    gemm2out_kernel<<<(NNODES + 63) / 64, 256, 0, stream>>>(h, W2l, W2r, b2, p, r, NNODES);
    gather_mean_kernel<64, true><<<(NNODES + 15) / 16, 256, 0, stream>>>(
        row_start, cursor, csr_src, p, r, out);
}

// Round 4
// 478.043 us; speedup vs baseline: 1.1529x; 1.1529x over previous
//
#include <hip/hip_runtime.h>

constexpr int NNODES = 100000;
constexpr int NEDGES = 1600000;
constexpr int K = 128;
constexpr int NB1 = (NNODES + 255) / 256;   // 391 scan blocks
constexpr int NSLICE = 8;
constexpr int NODES_PER_SLICE = NNODES / NSLICE;   // 12500
constexpr int FILL_BSLOTS = 256;
constexpr int EPB = NEDGES / FILL_BSLOTS;          // 6250 edges per block-slot

__global__ void zero_int_kernel(int* __restrict__ p, int n) {
    int i = blockIdx.x * 256 + threadIdx.x;
    if (i < n) p[i] = 0;
}

__global__ void hist_kernel(const int* __restrict__ dst, int* __restrict__ deg) {
    int e = blockIdx.x * 256 + threadIdx.x;
    if (e < NEDGES) atomicAdd(&deg[dst[e]], 1);
}

// exclusive scan, stage 1: per-256-block scan + block sums
__global__ void scan1_kernel(const int* __restrict__ deg, int* __restrict__ row_start,
                             int* __restrict__ blocksum) {
    __shared__ int tmp[256];
    int i = blockIdx.x * 256 + threadIdx.x;
    int v = (i < NNODES) ? deg[i] : 0;
    tmp[threadIdx.x] = v;
    __syncthreads();
    #pragma unroll
    for (int off = 1; off < 256; off <<= 1) {
        int t = (threadIdx.x >= off) ? tmp[threadIdx.x - off] : 0;
        __syncthreads();
        tmp[threadIdx.x] += t;
        __syncthreads();
    }
    if (i < NNODES) row_start[i] = tmp[threadIdx.x] - v;   // exclusive
    if (threadIdx.x == 255) blocksum[blockIdx.x] = tmp[255];
}

// stage 2: single block scans the 391 block sums (exclusive)
__global__ void scan2_kernel(int* __restrict__ blocksum, int* __restrict__ blockoff) {
    __shared__ int tmp[512];
    int t = threadIdx.x;
    int v = (t < NB1) ? blocksum[t] : 0;
    tmp[t] = v;
    __syncthreads();
    #pragma unroll
    for (int off = 1; off < 512; off <<= 1) {
        int u = (t >= off) ? tmp[t - off] : 0;
        __syncthreads();
        tmp[t] += u;
        __syncthreads();
    }
    if (t < NB1) blockoff[t] = tmp[t] - v;
}

// stage 3: add block offsets, init cursor = row_start
__global__ void scan3_kernel(int* __restrict__ row_start, const int* __restrict__ blockoff,
                             int* __restrict__ cursor) {
    int i = blockIdx.x * 256 + threadIdx.x;
    if (i < NNODES) {
        int rs = row_start[i] + blockoff[blockIdx.x];
        row_start[i] = rs;
        cursor[i] = rs;
    }
}

// XCD-sliced CSR fill: slice s (= blockIdx&7, lands on XCD s under round-robin)
// handles only dst in [s*12500, (s+1)*12500). Each slice's csr region (~800KB)
// + cursor slice (50KB) stay resident in ONE XCD's L2 -> lines accumulate all
// their 4B stores before writeback (kills the 16x write amplification).
__global__ void fill_sliced_kernel(const int* __restrict__ src, const int* __restrict__ dst,
                                   int* __restrict__ cursor, int* __restrict__ csr_src) {
    int bslot = blockIdx.x >> 3;          // 0..255: which edge chunk
    int slice = blockIdx.x & 7;           // 0..7: which node range / XCD
    int lo = slice * NODES_PER_SLICE;
    int hi = lo + NODES_PER_SLICE;
    int base = bslot * EPB;
    for (int e = base + threadIdx.x; e < base + EPB; e += 256) {
        int d = dst[e];
        if (d >= lo && d < hi) {
            int pos = atomicAdd(&cursor[d], 1);
            csr_src[pos] = src[e];
        }
    }
}

// bijective XCD swizzle (m204): block b -> chunk of contiguous blocks per XCD
__device__ __forceinline__ int xcd_swizzle(int bid, int nwg) {
    int xcd = bid & 7;
    int idx = bid >> 3;
    int q = nwg >> 3, r = nwg & 7;
    int base = (xcd < r) ? xcd * (q + 1) : r * (q + 1) + (xcd - r) * q;
    return base + idx;
}

// out[n] = mean over incoming neighbors of feat[src] (+ add[n] if ADDV)
template<int F, bool ADDV>
__global__ void gather_mean_kernel(const int* __restrict__ row_start,
                                   const int* __restrict__ row_end,
                                   const int* __restrict__ csr_src,
                                   const float* __restrict__ feat,
                                   const float* __restrict__ add,
                                   float* __restrict__ out, int nwg) {
    constexpr int G = F / 4;        // lanes per node (32 or 16)
    constexpr int NPB = 256 / G;    // nodes per block (8 or 16)
    int blk = xcd_swizzle(blockIdx.x, nwg);
    int node = blk * NPB + threadIdx.x / G;
    int lane = threadIdx.x % G;
    if (node >= NNODES) return;
    int beg = row_start[node];
    int end = row_end[node];
    float4 a0 = make_float4(0.f, 0.f, 0.f, 0.f);
    float4 a1 = make_float4(0.f, 0.f, 0.f, 0.f);
    float4 a2 = make_float4(0.f, 0.f, 0.f, 0.f);
    float4 a3 = make_float4(0.f, 0.f, 0.f, 0.f);
    int j = beg;
    for (; j + 3 < end; j += 4) {
        int s0 = csr_src[j];
        int s1 = csr_src[j + 1];
        int s2 = csr_src[j + 2];
        int s3 = csr_src[j + 3];
        float4 v0 = *reinterpret_cast<const float4*>(feat + (size_t)s0 * F + lane * 4);
        float4 v1 = *reinterpret_cast<const float4*>(feat + (size_t)s1 * F + lane * 4);
        float4 v2 = *reinterpret_cast<const float4*>(feat + (size_t)s2 * F + lane * 4);
        float4 v3 = *reinterpret_cast<const float4*>(feat + (size_t)s3 * F + lane * 4);
        a0.x += v0.x; a0.y += v0.y; a0.z += v0.z; a0.w += v0.w;
        a1.x += v1.x; a1.y += v1.y; a1.z += v1.z; a1.w += v1.w;
        a2.x += v2.x; a2.y += v2.y; a2.z += v2.z; a2.w += v2.w;
        a3.x += v3.x; a3.y += v3.y; a3.z += v3.z; a3.w += v3.w;
    }
    for (; j < end; ++j) {
        int s0 = csr_src[j];
        float4 v0 = *reinterpret_cast<const float4*>(feat + (size_t)s0 * F + lane * 4);
        a0.x += v0.x; a0.y += v0.y; a0.z += v0.z; a0.w += v0.w;
    }
    float inv = 1.0f / fmaxf((float)(end - beg), 1.0f);
    float4 o;
    o.x = (a0.x + a1.x + a2.x + a3.x) * inv;
    o.y = (a0.y + a1.y + a2.y + a3.y) * inv;
    o.z = (a0.z + a1.z + a2.z + a3.z) * inv;
    o.w = (a0.w + a1.w + a2.w + a3.w) * inv;
    if (ADDV) {
        float4 av = *reinterpret_cast<const float4*>(add + (size_t)node * F + lane * 4);
        o.x += av.x; o.y += av.y; o.z += av.z; o.w += av.w;
    }
    *reinterpret_cast<float4*>(out + (size_t)node * F + lane * 4) = o;
}

// C[r] = epi( A1[r]@Wa (+ A2[r]@Wb) + bias ); K=128 fixed.
template<int NOUT, bool TWO, bool RELU, bool BIAS>
__global__ __launch_bounds__(256, 2) void gemm_kernel(
    const float* __restrict__ A1, const float* __restrict__ Wa,
    const float* __restrict__ A2, const float* __restrict__ Wb,
    const float* __restrict__ bias,
    float* __restrict__ C, int M)
{
    constexpr int TM  = 64;
    constexpr int KC  = 32;
    constexpr int CT  = NOUT / 4;
    constexpr int RT  = 256 / CT;
    constexpr int RPT = TM / RT;

    __shared__ float As[KC][TM + 4];
    __shared__ float Ws[KC][NOUT];

    const int tid  = threadIdx.x;
    const int row0 = blockIdx.x * TM;

    const int arow   = tid >> 2;
    const int kq     = (tid & 3) * 8;
    const int lrow   = row0 + arow;
    const bool lvalid = lrow < M;

    const int tc = tid % CT;
    const int tr = tid / CT;

    float acc[RPT][4];
    #pragma unroll
    for (int i = 0; i < RPT; ++i)
        #pragma unroll
        for (int j = 0; j < 4; ++j) acc[i][j] = 0.f;

    #pragma unroll
    for (int mm = 0; mm < (TWO ? 2 : 1); ++mm) {
        const float* __restrict__ A = mm ? A2 : A1;
        const float* __restrict__ W = mm ? Wb : Wa;
        for (int kk = 0; kk < K; kk += KC) {
            float va[8];
            if (lvalid) {
                const float* ap = A + (size_t)lrow * K + kk + kq;
                float4 v0 = *reinterpret_cast<const float4*>(ap);
                float4 v1 = *reinterpret_cast<const float4*>(ap + 4);
                va[0] = v0.x; va[1] = v0.y; va[2] = v0.z; va[3] = v0.w;
                va[4] = v1.x; va[5] = v1.y; va[6] = v1.z; va[7] = v1.w;
            } else {
                #pragma unroll
                for (int j = 0; j < 8; ++j) va[j] = 0.f;
            }
            #pragma unroll
            for (int j = 0; j < 8; ++j) As[kq + j][arow] = va[j];

            constexpr int WQ = KC * NOUT / 4 / 256;
            const float4* wg = reinterpret_cast<const float4*>(W + kk * NOUT);
            float4* wl = reinterpret_cast<float4*>(&Ws[0][0]);
            #pragma unroll
            for (int q = 0; q < WQ; ++q) wl[tid + q * 256] = wg[tid + q * 256];

            __syncthreads();
            #pragma unroll
            for (int k = 0; k < KC; ++k) {
                float4 w = *reinterpret_cast<const float4*>(&Ws[k][tc * 4]);
                float a[RPT];
                #pragma unroll
                for (int q = 0; q < RPT; q += 4) {
                    float4 av = *reinterpret_cast<const float4*>(&As[k][tr * RPT + q]);
                    a[q] = av.x; a[q + 1] = av.y; a[q + 2] = av.z; a[q + 3] = av.w;
                }
                #pragma unroll
                for (int i = 0; i < RPT; ++i) {
                    acc[i][0] = fmaf(a[i], w.x, acc[i][0]);
                    acc[i][1] = fmaf(a[i], w.y, acc[i][1]);
                    acc[i][2] = fmaf(a[i], w.z, acc[i][2]);
                    acc[i][3] = fmaf(a[i], w.w, acc[i][3]);
                }
            }
            __syncthreads();
        }
    }

    float4 bv = make_float4(0.f, 0.f, 0.f, 0.f);
    if (BIAS) bv = *reinterpret_cast<const float4*>(bias + tc * 4);
    #pragma unroll
    for (int i = 0; i < RPT; ++i) {
        int r = row0 + tr * RPT + i;
        if (r >= M) continue;
        float4 o;
        o.x = acc[i][0] + bv.x; o.y = acc[i][1] + bv.y;
        o.z = acc[i][2] + bv.z; o.w = acc[i][3] + bv.w;
        if (RELU) {
            o.x = fmaxf(o.x, 0.f); o.y = fmaxf(o.y, 0.f);
            o.z = fmaxf(o.z, 0.f); o.w = fmaxf(o.w, 0.f);
        }
        *reinterpret_cast<float4*>(C + (size_t)r * NOUT + tc * 4) = o;
    }
}

// dual-output: P = A@Wl, R = A@Wr + bias   (single pass over A; NOUT=64, K=128)
__global__ __launch_bounds__(256, 2) void gemm2out_kernel(
    const float* __restrict__ A, const float* __restrict__ Wl,
    const float* __restrict__ Wr, const float* __restrict__ bias,
    float* __restrict__ P, float* __restrict__ R, int M)
{
    constexpr int TM = 64, KC = 32, NOUT = 64;
    constexpr int CT = 16, RPT = 4;

    __shared__ float As[KC][TM + 4];
    __shared__ float Wsl[KC][NOUT];
    __shared__ float Wsr[KC][NOUT];

    const int tid  = threadIdx.x;
    const int row0 = blockIdx.x * TM;
    const int arow = tid >> 2;
    const int kq   = (tid & 3) * 8;
    const int lrow = row0 + arow;
    const bool lvalid = lrow < M;
    const int tc = tid % CT;
    const int tr = tid / CT;

    float accp[RPT][4], accr[RPT][4];
    #pragma unroll
    for (int i = 0; i < RPT; ++i)
        #pragma unroll
        for (int j = 0; j < 4; ++j) { accp[i][j] = 0.f; accr[i][j] = 0.f; }

    for (int kk = 0; kk < K; kk += KC) {
        float va[8];
        if (lvalid) {
            const float* ap = A + (size_t)lrow * K + kk + kq;
            float4 v0 = *reinterpret_cast<const float4*>(ap);
            float4 v1 = *reinterpret_cast<const float4*>(ap + 4);
            va[0] = v0.x; va[1] = v0.y; va[2] = v0.z; va[3] = v0.w;
            va[4] = v1.x; va[5] = v1.y; va[6] = v1.z; va[7] = v1.w;
        } else {
            #pragma unroll
            for (int j = 0; j < 8; ++j) va[j] = 0.f;
        }
        #pragma unroll
        for (int j = 0; j < 8; ++j) As[kq + j][arow] = va[j];

        const float4* wgl = reinterpret_cast<const float4*>(Wl + kk * NOUT);
        const float4* wgr = reinterpret_cast<const float4*>(Wr + kk * NOUT);
        float4* wll = reinterpret_cast<float4*>(&Wsl[0][0]);
        float4* wlr = reinterpret_cast<float4*>(&Wsr[0][0]);
        wll[tid] = wgl[tid]; wll[tid + 256] = wgl[tid + 256];
        wlr[tid] = wgr[tid]; wlr[tid + 256] = wgr[tid + 256];

        __syncthreads();
        #pragma unroll
        for (int k = 0; k < KC; ++k) {
            float4 wl4 = *reinterpret_cast<const float4*>(&Wsl[k][tc * 4]);
            float4 wr4 = *reinterpret_cast<const float4*>(&Wsr[k][tc * 4]);
            float4 av = *reinterpret_cast<const float4*>(&As[k][tr * RPT]);
            float a[RPT] = {av.x, av.y, av.z, av.w};
            #pragma unroll
            for (int i = 0; i < RPT; ++i) {
                accp[i][0] = fmaf(a[i], wl4.x, accp[i][0]);
                accp[i][1] = fmaf(a[i], wl4.y, accp[i][1]);
                accp[i][2] = fmaf(a[i], wl4.z, accp[i][2]);
                accp[i][3] = fmaf(a[i], wl4.w, accp[i][3]);
                accr[i][0] = fmaf(a[i], wr4.x, accr[i][0]);
                accr[i][1] = fmaf(a[i], wr4.y, accr[i][1]);
                accr[i][2] = fmaf(a[i], wr4.z, accr[i][2]);
                accr[i][3] = fmaf(a[i], wr4.w, accr[i][3]);
            }
        }
        __syncthreads();
    }

    float4 bv = *reinterpret_cast<const float4*>(bias + tc * 4);
    #pragma unroll
    for (int i = 0; i < RPT; ++i) {
        int r = row0 + tr * RPT + i;
        if (r >= M) continue;
        float4 op, orr;
        op.x = accp[i][0]; op.y = accp[i][1]; op.z = accp[i][2]; op.w = accp[i][3];
        orr.x = accr[i][0] + bv.x; orr.y = accr[i][1] + bv.y;
        orr.z = accr[i][2] + bv.z; orr.w = accr[i][3] + bv.w;
        *reinterpret_cast<float4*>(P + (size_t)r * NOUT + tc * 4) = op;
        *reinterpret_cast<float4*>(R + (size_t)r * NOUT + tc * 4) = orr;
    }
}

extern "C" void kernel_launch(void* const* d_in, const int* in_sizes, int n_in,
                              void* d_out, int out_size, void* d_ws, size_t ws_size,
                              hipStream_t stream)
{
    const float* x   = (const float*)d_in[0];
    const int*   ei  = (const int*)d_in[1];
    const float* W1l = (const float*)d_in[2];
    const float* W1r = (const float*)d_in[3];
    const float* b1  = (const float*)d_in[4];
    const float* W2l = (const float*)d_in[5];
    const float* W2r = (const float*)d_in[6];
    const float* b2  = (const float*)d_in[7];
    const int* src = ei;
    const int* dst = ei + NEDGES;

    char* ws = (char*)d_ws;
    int*   deg_i     = (int*)(ws + 0);             // 400,000 B
    int*   row_start = (int*)(ws + 400128);        // 400,000 B
    int*   cursor    = (int*)(ws + 800256);        // 400,000 B (becomes row_end)
    int*   blocksum  = (int*)(ws + 1200384);
    int*   blockoff  = (int*)(ws + 1202048);
    int*   csr_src   = (int*)(ws + 1203712);       // 6,400,000 B
    float* agg1      = (float*)(ws + 7603712);     // 51,200,000 B (layer-1 agg)
    float* p         = agg1;                       // N*64 (reuse, layer-2 proj)
    float* r         = (float*)(ws + 7603712 + 25600000);  // N*64
    float* h         = (float*)(ws + 58803712);    // 51,200,000 B
    float* out       = (float*)d_out;

    // ---- build CSR (shared by both layers) ----
    zero_int_kernel<<<(NNODES + 255) / 256, 256, 0, stream>>>(deg_i, NNODES);
    hist_kernel<<<(NEDGES + 255) / 256, 256, 0, stream>>>(dst, deg_i);
    scan1_kernel<<<NB1, 256, 0, stream>>>(deg_i, row_start, blocksum);
    scan2_kernel<<<1, 512, 0, stream>>>(blocksum, blockoff);
    scan3_kernel<<<NB1, 256, 0, stream>>>(row_start, blockoff, cursor);
    fill_sliced_kernel<<<FILL_BSLOTS * NSLICE, 256, 0, stream>>>(src, dst, cursor, csr_src);

    // ---- layer 1 ----
    {
        int nwg = (NNODES + 7) / 8;
        gather_mean_kernel<128, false><<<nwg, 256, 0, stream>>>(
            row_start, cursor, csr_src, x, nullptr, agg1, nwg);
    }
    gemm_kernel<128, true, true, true>
        <<<(NNODES + 63) / 64, 256, 0, stream>>>(agg1, W1l, x, W1r, b1, h, NNODES);

    // ---- layer 2: p = h@W2_l, r = h@W2_r + b2 in one pass; out = mean(p) + r ----
    gemm2out_kernel<<<(NNODES + 63) / 64, 256, 0, stream>>>(h, W2l, W2r, b2, p, r, NNODES);
    {
        int nwg = (NNODES + 15) / 16;
        gather_mean_kernel<64, true><<<nwg, 256, 0, stream>>>(
            row_start, cursor, csr_src, p, r, out, nwg);
    }
}

// Round 5
// 413.100 us; speedup vs baseline: 1.3341x; 1.1572x over previous
//
#include <hip/hip_runtime.h>

constexpr int NNODES = 100000;
constexpr int NEDGES = 1600000;
constexpr int K = 128;
constexpr int NB1 = (NNODES + 255) / 256;   // 391 scan blocks
constexpr int NSLICE = 8;
constexpr int NODES_PER_SLICE = NNODES / NSLICE;   // 12500
constexpr int FILL_BSLOTS = 256;
constexpr int EPB = NEDGES / FILL_BSLOTS;          // 6250 edges per block-slot

__device__ __forceinline__ unsigned short f2bf(float f) {   // RTNE
    unsigned u = __float_as_uint(f);
    unsigned r = (u + 0x7fffu + ((u >> 16) & 1u)) >> 16;
    return (unsigned short)r;
}
__device__ __forceinline__ void acc2(float& a0, float& a1, unsigned u) {
    a0 += __uint_as_float(u << 16);
    a1 += __uint_as_float(u & 0xffff0000u);
}
__device__ __forceinline__ void acc8(float* a, uint4 v) {
    acc2(a[0], a[1], v.x); acc2(a[2], a[3], v.y);
    acc2(a[4], a[5], v.z); acc2(a[6], a[7], v.w);
}

__global__ void zero_int_kernel(int* __restrict__ p, int n) {
    int i = blockIdx.x * 256 + threadIdx.x;
    if (i < n) p[i] = 0;
}

// x (fp32) -> bf16, 8 elems/thread
__global__ void xcast_kernel(const float4* __restrict__ in, uint4* __restrict__ out, int n8) {
    int i = blockIdx.x * 256 + threadIdx.x;
    if (i >= n8) return;
    float4 a = in[2 * i], b = in[2 * i + 1];
    uint4 w;
    w.x = (unsigned)f2bf(a.x) | ((unsigned)f2bf(a.y) << 16);
    w.y = (unsigned)f2bf(a.z) | ((unsigned)f2bf(a.w) << 16);
    w.z = (unsigned)f2bf(b.x) | ((unsigned)f2bf(b.y) << 16);
    w.w = (unsigned)f2bf(b.z) | ((unsigned)f2bf(b.w) << 16);
    out[i] = w;
}

__global__ void hist_kernel(const int* __restrict__ dst, int* __restrict__ deg) {
    int e = blockIdx.x * 256 + threadIdx.x;
    if (e < NEDGES) atomicAdd(&deg[dst[e]], 1);
}

__global__ void scan1_kernel(const int* __restrict__ deg, int* __restrict__ row_start,
                             int* __restrict__ blocksum) {
    __shared__ int tmp[256];
    int i = blockIdx.x * 256 + threadIdx.x;
    int v = (i < NNODES) ? deg[i] : 0;
    tmp[threadIdx.x] = v;
    __syncthreads();
    #pragma unroll
    for (int off = 1; off < 256; off <<= 1) {
        int t = (threadIdx.x >= off) ? tmp[threadIdx.x - off] : 0;
        __syncthreads();
        tmp[threadIdx.x] += t;
        __syncthreads();
    }
    if (i < NNODES) row_start[i] = tmp[threadIdx.x] - v;   // exclusive
    if (threadIdx.x == 255) blocksum[blockIdx.x] = tmp[255];
}

__global__ void scan2_kernel(int* __restrict__ blocksum, int* __restrict__ blockoff) {
    __shared__ int tmp[512];
    int t = threadIdx.x;
    int v = (t < NB1) ? blocksum[t] : 0;
    tmp[t] = v;
    __syncthreads();
    #pragma unroll
    for (int off = 1; off < 512; off <<= 1) {
        int u = (t >= off) ? tmp[t - off] : 0;
        __syncthreads();
        tmp[t] += u;
        __syncthreads();
    }
    if (t < NB1) blockoff[t] = tmp[t] - v;
}

__global__ void scan3_kernel(int* __restrict__ row_start, const int* __restrict__ blockoff,
                             int* __restrict__ cursor) {
    int i = blockIdx.x * 256 + threadIdx.x;
    if (i < NNODES) {
        int rs = row_start[i] + blockoff[blockIdx.x];
        row_start[i] = rs;
        cursor[i] = rs;
    }
}

// XCD-sliced CSR fill (R3 win: keeps each slice's csr region in one XCD's L2)
__global__ void fill_sliced_kernel(const int* __restrict__ src, const int* __restrict__ dst,
                                   int* __restrict__ cursor, int* __restrict__ csr_src) {
    int bslot = blockIdx.x >> 3;
    int slice = blockIdx.x & 7;
    int lo = slice * NODES_PER_SLICE;
    int hi = lo + NODES_PER_SLICE;
    int base = bslot * EPB;
    for (int e = base + threadIdx.x; e < base + EPB; e += 256) {
        int d = dst[e];
        if (d >= lo && d < hi) {
            int pos = atomicAdd(&cursor[d], 1);
            csr_src[pos] = src[e];
        }
    }
}

// bijective XCD swizzle (m204)
__device__ __forceinline__ int xcd_swizzle(int bid, int nwg) {
    int xcd = bid & 7;
    int idx = bid >> 3;
    int q = nwg >> 3, r = nwg & 7;
    int base = (xcd < r) ? xcd * (q + 1) : r * (q + 1) + (xcd - r) * q;
    return base + idx;
}

// out[n] = mean over incoming neighbors of bf16 feat[src] (+ fp32 add[n] if ADDV)
// G = F/8 lanes per node, each lane handles 8 feature elems (16B bf16 loads).
template<int F, bool ADDV>
__global__ void gather_mean_bf16_kernel(const int* __restrict__ row_start,
                                        const int* __restrict__ row_end,
                                        const int* __restrict__ csr_src,
                                        const unsigned short* __restrict__ feat,
                                        const float* __restrict__ add,
                                        float* __restrict__ out, int nwg) {
    constexpr int G = F / 8;        // lanes per node (16 or 8)
    constexpr int NPB = 256 / G;    // nodes per block (16 or 32)
    int blk = xcd_swizzle(blockIdx.x, nwg);
    int node = blk * NPB + threadIdx.x / G;
    int lane = threadIdx.x % G;
    if (node >= NNODES) return;
    int beg = row_start[node];
    int end = row_end[node];
    const uint4* fp = reinterpret_cast<const uint4*>(feat);   // row = G uint4s
    float a[8];
    #pragma unroll
    for (int q = 0; q < 8; ++q) a[q] = 0.f;
    int j = beg;
    for (; j + 3 < end; j += 4) {
        int s0 = csr_src[j];
        int s1 = csr_src[j + 1];
        int s2 = csr_src[j + 2];
        int s3 = csr_src[j + 3];
        uint4 v0 = fp[(size_t)s0 * G + lane];
        uint4 v1 = fp[(size_t)s1 * G + lane];
        uint4 v2 = fp[(size_t)s2 * G + lane];
        uint4 v3 = fp[(size_t)s3 * G + lane];
        acc8(a, v0); acc8(a, v1); acc8(a, v2); acc8(a, v3);
    }
    for (; j < end; ++j) {
        uint4 v0 = fp[(size_t)csr_src[j] * G + lane];
        acc8(a, v0);
    }
    float inv = 1.0f / fmaxf((float)(end - beg), 1.0f);
    float4 o0, o1;
    o0.x = a[0] * inv; o0.y = a[1] * inv; o0.z = a[2] * inv; o0.w = a[3] * inv;
    o1.x = a[4] * inv; o1.y = a[5] * inv; o1.z = a[6] * inv; o1.w = a[7] * inv;
    if (ADDV) {
        const float4* ap = reinterpret_cast<const float4*>(add + (size_t)node * F + lane * 8);
        float4 r0 = ap[0], r1 = ap[1];
        o0.x += r0.x; o0.y += r0.y; o0.z += r0.z; o0.w += r0.w;
        o1.x += r1.x; o1.y += r1.y; o1.z += r1.z; o1.w += r1.w;
    }
    float4* op = reinterpret_cast<float4*>(out + (size_t)node * F + lane * 8);
    op[0] = o0; op[1] = o1;
}

// C[r] = epi( A1[r]@Wa (+ A2[r]@Wb) + bias ); K=128 fixed.
template<int NOUT, bool TWO, bool RELU, bool BIAS>
__global__ __launch_bounds__(256, 2) void gemm_kernel(
    const float* __restrict__ A1, const float* __restrict__ Wa,
    const float* __restrict__ A2, const float* __restrict__ Wb,
    const float* __restrict__ bias,
    float* __restrict__ C, int M)
{
    constexpr int TM  = 64;
    constexpr int KC  = 32;
    constexpr int CT  = NOUT / 4;
    constexpr int RT  = 256 / CT;
    constexpr int RPT = TM / RT;

    __shared__ float As[KC][TM + 4];
    __shared__ float Ws[KC][NOUT];

    const int tid  = threadIdx.x;
    const int row0 = blockIdx.x * TM;

    const int arow   = tid >> 2;
    const int kq     = (tid & 3) * 8;
    const int lrow   = row0 + arow;
    const bool lvalid = lrow < M;

    const int tc = tid % CT;
    const int tr = tid / CT;

    float acc[RPT][4];
    #pragma unroll
    for (int i = 0; i < RPT; ++i)
        #pragma unroll
        for (int j = 0; j < 4; ++j) acc[i][j] = 0.f;

    #pragma unroll
    for (int mm = 0; mm < (TWO ? 2 : 1); ++mm) {
        const float* __restrict__ A = mm ? A2 : A1;
        const float* __restrict__ W = mm ? Wb : Wa;
        for (int kk = 0; kk < K; kk += KC) {
            float va[8];
            if (lvalid) {
                const float* ap = A + (size_t)lrow * K + kk + kq;
                float4 v0 = *reinterpret_cast<const float4*>(ap);
                float4 v1 = *reinterpret_cast<const float4*>(ap + 4);
                va[0] = v0.x; va[1] = v0.y; va[2] = v0.z; va[3] = v0.w;
                va[4] = v1.x; va[5] = v1.y; va[6] = v1.z; va[7] = v1.w;
            } else {
                #pragma unroll
                for (int j = 0; j < 8; ++j) va[j] = 0.f;
            }
            #pragma unroll
            for (int j = 0; j < 8; ++j) As[kq + j][arow] = va[j];

            constexpr int WQ = KC * NOUT / 4 / 256;
            const float4* wg = reinterpret_cast<const float4*>(W + kk * NOUT);
            float4* wl = reinterpret_cast<float4*>(&Ws[0][0]);
            #pragma unroll
            for (int q = 0; q < WQ; ++q) wl[tid + q * 256] = wg[tid + q * 256];

            __syncthreads();
            #pragma unroll
            for (int k = 0; k < KC; ++k) {
                float4 w = *reinterpret_cast<const float4*>(&Ws[k][tc * 4]);
                float a[RPT];
                #pragma unroll
                for (int q = 0; q < RPT; q += 4) {
                    float4 av = *reinterpret_cast<const float4*>(&As[k][tr * RPT + q]);
                    a[q] = av.x; a[q + 1] = av.y; a[q + 2] = av.z; a[q + 3] = av.w;
                }
                #pragma unroll
                for (int i = 0; i < RPT; ++i) {
                    acc[i][0] = fmaf(a[i], w.x, acc[i][0]);
                    acc[i][1] = fmaf(a[i], w.y, acc[i][1]);
                    acc[i][2] = fmaf(a[i], w.z, acc[i][2]);
                    acc[i][3] = fmaf(a[i], w.w, acc[i][3]);
                }
            }
            __syncthreads();
        }
    }

    float4 bv = make_float4(0.f, 0.f, 0.f, 0.f);
    if (BIAS) bv = *reinterpret_cast<const float4*>(bias + tc * 4);
    #pragma unroll
    for (int i = 0; i < RPT; ++i) {
        int r = row0 + tr * RPT + i;
        if (r >= M) continue;
        float4 o;
        o.x = acc[i][0] + bv.x; o.y = acc[i][1] + bv.y;
        o.z = acc[i][2] + bv.z; o.w = acc[i][3] + bv.w;
        if (RELU) {
            o.x = fmaxf(o.x, 0.f); o.y = fmaxf(o.y, 0.f);
            o.z = fmaxf(o.z, 0.f); o.w = fmaxf(o.w, 0.f);
        }
        *reinterpret_cast<float4*>(C + (size_t)r * NOUT + tc * 4) = o;
    }
}

// dual-output: P(bf16) = A@Wl, R(fp32) = A@Wr + bias  (one pass over A; NOUT=64)
__global__ __launch_bounds__(256, 2) void gemm2out_kernel(
    const float* __restrict__ A, const float* __restrict__ Wl,
    const float* __restrict__ Wr, const float* __restrict__ bias,
    unsigned short* __restrict__ P, float* __restrict__ R, int M)
{
    constexpr int TM = 64, KC = 32, NOUT = 64;
    constexpr int CT = 16, RPT = 4;

    __shared__ float As[KC][TM + 4];
    __shared__ float Wsl[KC][NOUT];
    __shared__ float Wsr[KC][NOUT];

    const int tid  = threadIdx.x;
    const int row0 = blockIdx.x * TM;
    const int arow = tid >> 2;
    const int kq   = (tid & 3) * 8;
    const int lrow = row0 + arow;
    const bool lvalid = lrow < M;
    const int tc = tid % CT;
    const int tr = tid / CT;

    float accp[RPT][4], accr[RPT][4];
    #pragma unroll
    for (int i = 0; i < RPT; ++i)
        #pragma unroll
        for (int j = 0; j < 4; ++j) { accp[i][j] = 0.f; accr[i][j] = 0.f; }

    for (int kk = 0; kk < K; kk += KC) {
        float va[8];
        if (lvalid) {
            const float* ap = A + (size_t)lrow * K + kk + kq;
            float4 v0 = *reinterpret_cast<const float4*>(ap);
            float4 v1 = *reinterpret_cast<const float4*>(ap + 4);
            va[0] = v0.x; va[1] = v0.y; va[2] = v0.z; va[3] = v0.w;
            va[4] = v1.x; va[5] = v1.y; va[6] = v1.z; va[7] = v1.w;
        } else {
            #pragma unroll
            for (int j = 0; j < 8; ++j) va[j] = 0.f;
        }
        #pragma unroll
        for (int j = 0; j < 8; ++j) As[kq + j][arow] = va[j];

        const float4* wgl = reinterpret_cast<const float4*>(Wl + kk * NOUT);
        const float4* wgr = reinterpret_cast<const float4*>(Wr + kk * NOUT);
        float4* wll = reinterpret_cast<float4*>(&Wsl[0][0]);
        float4* wlr = reinterpret_cast<float4*>(&Wsr[0][0]);
        wll[tid] = wgl[tid]; wll[tid + 256] = wgl[tid + 256];
        wlr[tid] = wgr[tid]; wlr[tid + 256] = wgr[tid + 256];

        __syncthreads();
        #pragma unroll
        for (int k = 0; k < KC; ++k) {
            float4 wl4 = *reinterpret_cast<const float4*>(&Wsl[k][tc * 4]);
            float4 wr4 = *reinterpret_cast<const float4*>(&Wsr[k][tc * 4]);
            float4 av = *reinterpret_cast<const float4*>(&As[k][tr * RPT]);
            float a[RPT] = {av.x, av.y, av.z, av.w};
            #pragma unroll
            for (int i = 0; i < RPT; ++i) {
                accp[i][0] = fmaf(a[i], wl4.x, accp[i][0]);
                accp[i][1] = fmaf(a[i], wl4.y, accp[i][1]);
                accp[i][2] = fmaf(a[i], wl4.z, accp[i][2]);
                accp[i][3] = fmaf(a[i], wl4.w, accp[i][3]);
                accr[i][0] = fmaf(a[i], wr4.x, accr[i][0]);
                accr[i][1] = fmaf(a[i], wr4.y, accr[i][1]);
                accr[i][2] = fmaf(a[i], wr4.z, accr[i][2]);
                accr[i][3] = fmaf(a[i], wr4.w, accr[i][3]);
            }
        }
        __syncthreads();
    }

    float4 bv = *reinterpret_cast<const float4*>(bias + tc * 4);
    #pragma unroll
    for (int i = 0; i < RPT; ++i) {
        int r = row0 + tr * RPT + i;
        if (r >= M) continue;
        uint2 pw;
        pw.x = (unsigned)f2bf(accp[i][0]) | ((unsigned)f2bf(accp[i][1]) << 16);
        pw.y = (unsigned)f2bf(accp[i][2]) | ((unsigned)f2bf(accp[i][3]) << 16);
        *reinterpret_cast<uint2*>(P + (size_t)r * NOUT + tc * 4) = pw;
        float4 orr;
        orr.x = accr[i][0] + bv.x; orr.y = accr[i][1] + bv.y;
        orr.z = accr[i][2] + bv.z; orr.w = accr[i][3] + bv.w;
        *reinterpret_cast<float4*>(R + (size_t)r * NOUT + tc * 4) = orr;
    }
}

extern "C" void kernel_launch(void* const* d_in, const int* in_sizes, int n_in,
                              void* d_out, int out_size, void* d_ws, size_t ws_size,
                              hipStream_t stream)
{
    const float* x   = (const float*)d_in[0];
    const int*   ei  = (const int*)d_in[1];
    const float* W1l = (const float*)d_in[2];
    const float* W1r = (const float*)d_in[3];
    const float* b1  = (const float*)d_in[4];
    const float* W2l = (const float*)d_in[5];
    const float* W2r = (const float*)d_in[6];
    const float* b2  = (const float*)d_in[7];
    const int* src = ei;
    const int* dst = ei + NEDGES;

    char* ws = (char*)d_ws;
    int*   deg_i     = (int*)(ws + 0);             // 400,000 B
    int*   row_start = (int*)(ws + 400128);        // 400,000 B
    int*   cursor    = (int*)(ws + 800256);        // 400,000 B (becomes row_end)
    int*   blocksum  = (int*)(ws + 1200384);
    int*   blockoff  = (int*)(ws + 1202048);
    int*   csr_src   = (int*)(ws + 1203712);       // 6,400,000 B
    float* agg1      = (float*)(ws + 7603712);     // 51,200,000 B (layer-1 agg)
    unsigned short* p = (unsigned short*)(ws + 7603712);          // N*64 bf16 (reuse)
    float* r         = (float*)(ws + 7603712 + 12800000);         // N*64 fp32
    float* h         = (float*)(ws + 58803712);    // 51,200,000 B
    unsigned short* x_bf16 = (unsigned short*)(ws + 58803712);    // 25.6 MB, dead before h written
    float* out       = (float*)d_out;

    // ---- build CSR (shared by both layers) + bf16 cast of x ----
    zero_int_kernel<<<(NNODES + 255) / 256, 256, 0, stream>>>(deg_i, NNODES);
    hist_kernel<<<(NEDGES + 255) / 256, 256, 0, stream>>>(dst, deg_i);
    xcast_kernel<<<(NNODES * K / 8 + 255) / 256, 256, 0, stream>>>(
        (const float4*)x, (uint4*)x_bf16, NNODES * K / 8);
    scan1_kernel<<<NB1, 256, 0, stream>>>(deg_i, row_start, blocksum);
    scan2_kernel<<<1, 512, 0, stream>>>(blocksum, blockoff);
    scan3_kernel<<<NB1, 256, 0, stream>>>(row_start, blockoff, cursor);
    fill_sliced_kernel<<<FILL_BSLOTS * NSLICE, 256, 0, stream>>>(src, dst, cursor, csr_src);

    // ---- layer 1 ----
    {
        int nwg = (NNODES + 15) / 16;
        gather_mean_bf16_kernel<128, false><<<nwg, 256, 0, stream>>>(
            row_start, cursor, csr_src, x_bf16, nullptr, agg1, nwg);
    }
    gemm_kernel<128, true, true, true>
        <<<(NNODES + 63) / 64, 256, 0, stream>>>(agg1, W1l, x, W1r, b1, h, NNODES);

    // ---- layer 2: p(bf16) = h@W2_l, r = h@W2_r + b2; out = mean(p) + r ----
    gemm2out_kernel<<<(NNODES + 63) / 64, 256, 0, stream>>>(h, W2l, W2r, b2, p, r, NNODES);
    {
        int nwg = (NNODES + 31) / 32;
        gather_mean_bf16_kernel<64, true><<<nwg, 256, 0, stream>>>(
            row_start, cursor, csr_src, p, r, out, nwg);
    }
}

// Round 6
// 350.547 us; speedup vs baseline: 1.5722x; 1.1784x over previous
//
#include <hip/hip_runtime.h>

constexpr int NNODES = 100000;
constexpr int NEDGES = 1600000;
constexpr int K = 128;
constexpr int NB1 = (NNODES + 255) / 256;   // 391 scan blocks
constexpr int NSLICE = 8;
constexpr int NODES_PER_SLICE = NNODES / NSLICE;   // 12500
constexpr int FILL_BSLOTS = 256;
constexpr int EPB = NEDGES / FILL_BSLOTS;          // 6250 edges per block-slot

typedef __attribute__((ext_vector_type(8))) short bf16x8;
typedef __attribute__((ext_vector_type(4))) float f32x4;

__device__ __forceinline__ unsigned short f2bf(float f) {   // RTNE
    unsigned u = __float_as_uint(f);
    unsigned r = (u + 0x7fffu + ((u >> 16) & 1u)) >> 16;
    return (unsigned short)r;
}
__device__ __forceinline__ void acc2(float& a0, float& a1, unsigned u) {
    a0 += __uint_as_float(u << 16);
    a1 += __uint_as_float(u & 0xffff0000u);
}
__device__ __forceinline__ void acc8(float* a, uint4 v) {
    acc2(a[0], a[1], v.x); acc2(a[2], a[3], v.y);
    acc2(a[4], a[5], v.z); acc2(a[6], a[7], v.w);
}

__global__ void zero_int_kernel(int* __restrict__ p, int n) {
    int i = blockIdx.x * 256 + threadIdx.x;
    if (i < n) p[i] = 0;
}

// x (fp32) -> bf16, 8 elems/thread
__global__ void xcast_kernel(const float4* __restrict__ in, uint4* __restrict__ out, int n8) {
    int i = blockIdx.x * 256 + threadIdx.x;
    if (i >= n8) return;
    float4 a = in[2 * i], b = in[2 * i + 1];
    uint4 w;
    w.x = (unsigned)f2bf(a.x) | ((unsigned)f2bf(a.y) << 16);
    w.y = (unsigned)f2bf(a.z) | ((unsigned)f2bf(a.w) << 16);
    w.z = (unsigned)f2bf(b.x) | ((unsigned)f2bf(b.y) << 16);
    w.w = (unsigned)f2bf(b.z) | ((unsigned)f2bf(b.w) << 16);
    out[i] = w;
}

// cast + transpose weights to bf16 [N][K]; Wt2 = concat([W2l|W2r] cols)
__global__ void wprep_kernel(const float* __restrict__ W1l, const float* __restrict__ W1r,
                             const float* __restrict__ W2l, const float* __restrict__ W2r,
                             unsigned short* __restrict__ Wt1l, unsigned short* __restrict__ Wt1r,
                             unsigned short* __restrict__ Wt2) {
    int idx = blockIdx.x * 256 + threadIdx.x;     // [n][k], n-major
    if (idx >= 128 * 128) return;
    int n = idx >> 7, k = idx & 127;
    Wt1l[idx] = f2bf(W1l[k * 128 + n]);
    Wt1r[idx] = f2bf(W1r[k * 128 + n]);
    Wt2[idx]  = f2bf(n < 64 ? W2l[k * 64 + n] : W2r[k * 64 + (n - 64)]);
}

__global__ void hist_kernel(const int* __restrict__ dst, int* __restrict__ deg) {
    int e = blockIdx.x * 256 + threadIdx.x;
    if (e < NEDGES) atomicAdd(&deg[dst[e]], 1);
}

__global__ void scan1_kernel(const int* __restrict__ deg, int* __restrict__ row_start,
                             int* __restrict__ blocksum) {
    __shared__ int tmp[256];
    int i = blockIdx.x * 256 + threadIdx.x;
    int v = (i < NNODES) ? deg[i] : 0;
    tmp[threadIdx.x] = v;
    __syncthreads();
    #pragma unroll
    for (int off = 1; off < 256; off <<= 1) {
        int t = (threadIdx.x >= off) ? tmp[threadIdx.x - off] : 0;
        __syncthreads();
        tmp[threadIdx.x] += t;
        __syncthreads();
    }
    if (i < NNODES) row_start[i] = tmp[threadIdx.x] - v;   // exclusive
    if (threadIdx.x == 255) blocksum[blockIdx.x] = tmp[255];
}

__global__ void scan2_kernel(int* __restrict__ blocksum, int* __restrict__ blockoff) {
    __shared__ int tmp[512];
    int t = threadIdx.x;
    int v = (t < NB1) ? blocksum[t] : 0;
    tmp[t] = v;
    __syncthreads();
    #pragma unroll
    for (int off = 1; off < 512; off <<= 1) {
        int u = (t >= off) ? tmp[t - off] : 0;
        __syncthreads();
        tmp[t] += u;
        __syncthreads();
    }
    if (t < NB1) blockoff[t] = tmp[t] - v;
}

__global__ void scan3_kernel(int* __restrict__ row_start, const int* __restrict__ blockoff,
                             int* __restrict__ cursor) {
    int i = blockIdx.x * 256 + threadIdx.x;
    if (i < NNODES) {
        int rs = row_start[i] + blockoff[blockIdx.x];
        row_start[i] = rs;
        cursor[i] = rs;
    }
}

// XCD-sliced CSR fill (R3 win: keeps each slice's csr region in one XCD's L2)
__global__ void fill_sliced_kernel(const int* __restrict__ src, const int* __restrict__ dst,
                                   int* __restrict__ cursor, int* __restrict__ csr_src) {
    int bslot = blockIdx.x >> 3;
    int slice = blockIdx.x & 7;
    int lo = slice * NODES_PER_SLICE;
    int hi = lo + NODES_PER_SLICE;
    int base = bslot * EPB;
    for (int e = base + threadIdx.x; e < base + EPB; e += 256) {
        int d = dst[e];
        if (d >= lo && d < hi) {
            int pos = atomicAdd(&cursor[d], 1);
            csr_src[pos] = src[e];
        }
    }
}

// bijective XCD swizzle (m204)
__device__ __forceinline__ int xcd_swizzle(int bid, int nwg) {
    int xcd = bid & 7;
    int idx = bid >> 3;
    int q = nwg >> 3, r = nwg & 7;
    int base = (xcd < r) ? xcd * (q + 1) : r * (q + 1) + (xcd - r) * q;
    return base + idx;
}

// out[n] = mean over incoming neighbors of bf16 feat[src] (+ fp32 add[n] if ADDV)
// OUTBF: emit bf16 (16B/lane) instead of fp32.
template<int F, bool ADDV, bool OUTBF>
__global__ void gather_mean_bf16_kernel(const int* __restrict__ row_start,
                                        const int* __restrict__ row_end,
                                        const int* __restrict__ csr_src,
                                        const unsigned short* __restrict__ feat,
                                        const float* __restrict__ add,
                                        void* __restrict__ outp, int nwg) {
    constexpr int G = F / 8;        // lanes per node (16 or 8)
    constexpr int NPB = 256 / G;    // nodes per block (16 or 32)
    int blk = xcd_swizzle(blockIdx.x, nwg);
    int node = blk * NPB + threadIdx.x / G;
    int lane = threadIdx.x % G;
    if (node >= NNODES) return;
    int beg = row_start[node];
    int end = row_end[node];
    const uint4* fp = reinterpret_cast<const uint4*>(feat);   // row = G uint4s
    float a[8];
    #pragma unroll
    for (int q = 0; q < 8; ++q) a[q] = 0.f;
    int j = beg;
    for (; j + 3 < end; j += 4) {
        int s0 = csr_src[j];
        int s1 = csr_src[j + 1];
        int s2 = csr_src[j + 2];
        int s3 = csr_src[j + 3];
        uint4 v0 = fp[(size_t)s0 * G + lane];
        uint4 v1 = fp[(size_t)s1 * G + lane];
        uint4 v2 = fp[(size_t)s2 * G + lane];
        uint4 v3 = fp[(size_t)s3 * G + lane];
        acc8(a, v0); acc8(a, v1); acc8(a, v2); acc8(a, v3);
    }
    for (; j < end; ++j) {
        uint4 v0 = fp[(size_t)csr_src[j] * G + lane];
        acc8(a, v0);
    }
    float inv = 1.0f / fmaxf((float)(end - beg), 1.0f);
    #pragma unroll
    for (int q = 0; q < 8; ++q) a[q] *= inv;
    if (OUTBF) {
        uint4 w;
        w.x = (unsigned)f2bf(a[0]) | ((unsigned)f2bf(a[1]) << 16);
        w.y = (unsigned)f2bf(a[2]) | ((unsigned)f2bf(a[3]) << 16);
        w.z = (unsigned)f2bf(a[4]) | ((unsigned)f2bf(a[5]) << 16);
        w.w = (unsigned)f2bf(a[6]) | ((unsigned)f2bf(a[7]) << 16);
        reinterpret_cast<uint4*>(outp)[(size_t)node * G + lane] = w;
    } else {
        float4 o0, o1;
        o0.x = a[0]; o0.y = a[1]; o0.z = a[2]; o0.w = a[3];
        o1.x = a[4]; o1.y = a[5]; o1.z = a[6]; o1.w = a[7];
        if (ADDV) {
            const float4* ap = reinterpret_cast<const float4*>(add + (size_t)node * F + lane * 8);
            float4 r0 = ap[0], r1 = ap[1];
            o0.x += r0.x; o0.y += r0.y; o0.z += r0.z; o0.w += r0.w;
            o1.x += r1.x; o1.y += r1.y; o1.z += r1.z; o1.w += r1.w;
        }
        float4* op = reinterpret_cast<float4*>((float*)outp + (size_t)node * F + lane * 8);
        op[0] = o0; op[1] = o1;
    }
}

// bf16 MFMA GEMM, K=128, N=128, 64 rows/block (4 waves x 16 rows).
// A/B frag: lane holds 8 contiguous k at k = (lane>>4)*8; A row / B col = lane&15.
// C/D: col = lane&15, row = (lane>>4)*4 + reg  [m89 verified].
// LAYER2=false: h = relu(A1@Wt1^T + A2@Wt2^T + bias), bf16 out.
// LAYER2=true:  cols 0-63 -> outB (bf16, no bias); cols 64-127 -> outF (fp32, +bias).
template<bool LAYER2>
__global__ __launch_bounds__(256) void mfma_gemm_kernel(
    const unsigned short* __restrict__ A1, const unsigned short* __restrict__ A2,
    const unsigned short* __restrict__ Wt1, const unsigned short* __restrict__ Wt2,
    const float* __restrict__ bias,
    unsigned short* __restrict__ outB, float* __restrict__ outF, int M)
{
    const int wave = threadIdx.x >> 6;
    const int lane = threadIdx.x & 63;
    const int rsub = lane & 15;
    const int kgrp = lane >> 4;
    const int koff = kgrp * 8;
    const int row0 = blockIdx.x * 64 + wave * 16;
    const int arow = row0 + rsub;
    const bool avalid = arow < M;

    f32x4 acc[8];
    #pragma unroll
    for (int n = 0; n < 8; ++n) acc[n] = (f32x4){0.f, 0.f, 0.f, 0.f};

    #pragma unroll
    for (int mat = 0; mat < (LAYER2 ? 1 : 2); ++mat) {
        const unsigned short* __restrict__ A = mat ? A2 : A1;
        const unsigned short* __restrict__ W = mat ? Wt2 : Wt1;
        #pragma unroll
        for (int kk = 0; kk < 128; kk += 32) {
            bf16x8 af = {0, 0, 0, 0, 0, 0, 0, 0};
            if (avalid)
                af = *reinterpret_cast<const bf16x8*>(A + (size_t)arow * 128 + kk + koff);
            bf16x8 bfr[8];
            #pragma unroll
            for (int n = 0; n < 8; ++n)
                bfr[n] = *reinterpret_cast<const bf16x8*>(W + (size_t)(n * 16 + rsub) * 128 + kk + koff);
            #pragma unroll
            for (int n = 0; n < 8; ++n)
                acc[n] = __builtin_amdgcn_mfma_f32_16x16x32_bf16(af, bfr[n], acc[n], 0, 0, 0);
        }
    }

    const int orow0 = row0 + kgrp * 4;
    if (!LAYER2) {
        float bv[8];
        #pragma unroll
        for (int n = 0; n < 8; ++n) bv[n] = bias[n * 16 + rsub];
        #pragma unroll
        for (int reg = 0; reg < 4; ++reg) {
            int orow = orow0 + reg;
            if (orow < M) {
                #pragma unroll
                for (int n = 0; n < 8; ++n) {
                    float v = fmaxf(acc[n][reg] + bv[n], 0.f);
                    outB[(size_t)orow * 128 + n * 16 + rsub] = f2bf(v);
                }
            }
        }
    } else {
        float bv[4];
        #pragma unroll
        for (int n = 0; n < 4; ++n) bv[n] = bias[n * 16 + rsub];
        #pragma unroll
        for (int reg = 0; reg < 4; ++reg) {
            int orow = orow0 + reg;
            if (orow < M) {
                #pragma unroll
                for (int n = 0; n < 4; ++n)
                    outB[(size_t)orow * 64 + n * 16 + rsub] = f2bf(acc[n][reg]);
                #pragma unroll
                for (int n = 0; n < 4; ++n)
                    outF[(size_t)orow * 64 + n * 16 + rsub] = acc[n + 4][reg] + bv[n];
            }
        }
    }
}

extern "C" void kernel_launch(void* const* d_in, const int* in_sizes, int n_in,
                              void* d_out, int out_size, void* d_ws, size_t ws_size,
                              hipStream_t stream)
{
    const float* x   = (const float*)d_in[0];
    const int*   ei  = (const int*)d_in[1];
    const float* W1l = (const float*)d_in[2];
    const float* W1r = (const float*)d_in[3];
    const float* b1  = (const float*)d_in[4];
    const float* W2l = (const float*)d_in[5];
    const float* W2r = (const float*)d_in[6];
    const float* b2  = (const float*)d_in[7];
    const int* src = ei;
    const int* dst = ei + NEDGES;

    char* ws = (char*)d_ws;
    int*   deg_i     = (int*)(ws + 0);                    // 400,000 B
    int*   row_start = (int*)(ws + 400128);               // 400,000 B
    int*   cursor    = (int*)(ws + 800256);               // 400,000 B (becomes row_end)
    int*   blocksum  = (int*)(ws + 1200384);
    int*   blockoff  = (int*)(ws + 1202048);
    unsigned short* Wt1l = (unsigned short*)(ws + 1203712);   // 32 KB bf16 [n][k]
    unsigned short* Wt1r = (unsigned short*)(ws + 1236480);   // 32 KB
    unsigned short* Wt2  = (unsigned short*)(ws + 1269248);   // 32 KB ([W2l|W2r] cols)
    int*   csr_src   = (int*)(ws + 1302016);              // 6,400,000 B
    unsigned short* agg1b = (unsigned short*)(ws + 7702016);  // N*128 bf16 (25.6 MB)
    unsigned short* p     = (unsigned short*)(ws + 7702016);  // N*64 bf16 (reuse after gemm1)
    float* r         = (float*)(ws + 20502016);           // N*64 fp32 (25.6 MB)
    unsigned short* h_bf16 = (unsigned short*)(ws + 46102016);// N*128 bf16 (25.6 MB)
    unsigned short* x_bf16 = (unsigned short*)(ws + 71702016);// N*128 bf16 (25.6 MB)
    float* out       = (float*)d_out;

    // ---- CSR build + casts (independent prep) ----
    zero_int_kernel<<<(NNODES + 255) / 256, 256, 0, stream>>>(deg_i, NNODES);
    hist_kernel<<<(NEDGES + 255) / 256, 256, 0, stream>>>(dst, deg_i);
    xcast_kernel<<<(NNODES * K / 8 + 255) / 256, 256, 0, stream>>>(
        (const float4*)x, (uint4*)x_bf16, NNODES * K / 8);
    wprep_kernel<<<64, 256, 0, stream>>>(W1l, W1r, W2l, W2r, Wt1l, Wt1r, Wt2);
    scan1_kernel<<<NB1, 256, 0, stream>>>(deg_i, row_start, blocksum);
    scan2_kernel<<<1, 512, 0, stream>>>(blocksum, blockoff);
    scan3_kernel<<<NB1, 256, 0, stream>>>(row_start, blockoff, cursor);
    fill_sliced_kernel<<<FILL_BSLOTS * NSLICE, 256, 0, stream>>>(src, dst, cursor, csr_src);

    // ---- layer 1: agg1b = mean(x_bf16[nbrs]) (bf16); h = relu(agg1b@W1l + x@W1r + b1) ----
    {
        int nwg = (NNODES + 15) / 16;
        gather_mean_bf16_kernel<128, false, true><<<nwg, 256, 0, stream>>>(
            row_start, cursor, csr_src, x_bf16, nullptr, agg1b, nwg);
    }
    mfma_gemm_kernel<false><<<(NNODES + 63) / 64, 256, 0, stream>>>(
        agg1b, x_bf16, Wt1l, Wt1r, b1, h_bf16, nullptr, NNODES);

    // ---- layer 2: [p|r] = h@[W2l|W2r] (+b2 on r); out = mean(p[nbrs]) + r ----
    mfma_gemm_kernel<true><<<(NNODES + 63) / 64, 256, 0, stream>>>(
        h_bf16, nullptr, Wt2, nullptr, b2, p, r, NNODES);
    {
        int nwg = (NNODES + 31) / 32;
        gather_mean_bf16_kernel<64, true, false><<<nwg, 256, 0, stream>>>(
            row_start, cursor, csr_src, p, r, out, nwg);
    }
}